// Round 3
// baseline (103.679 us; speedup 1.0000x reference)
//
#include <hip/hip_runtime.h>
#include <math.h>

// RRoIAlign: features (8,32,160,160) f32, rois (1024,6) f32
// out (1024,32,8,64) f32.  POOLED_H=8, POOLED_W=64, SPATIAL_SCALE=0.25
//
// R10: zero-LDS, zero-barrier rroi.
//  - Predicated gather: corner loads skipped when their (exactly-zero)
//    weight is 0 (rx==0 => dx==0 => duplicate address anyway). Cuts gather
//    instructions/L1-txns from 4 to ~2.25 per thread avg; registers
//    zero-inited so blend contributes exact 0 (matches reference validity
//    zeroing).
//  - Direct NT stores: for fixed channel, the wave's 16 lanes (bl_=t>>2)
//    write 16 consecutive floats = one full 64B line per store inst, so the
//    s_out LDS transpose + final barrier are pure overhead -> removed.
// R9: per-thread register geometry (4x redundant VALU is free - parallel).
// R7: fp16 NHWC intermediate (halves transpose-trick HBM overhead).
//
// NUMERICS (frozen since R1): geometry fp contract(off) + reference op order;
// trig double->f32; blend ((w0*a+w1*b)+w2*c)+w3*d contract off. Do not
// re-order. absmax 0.03125 (fp16 feature rounding), threshold-safe.

#define C_ 32
#define H_ 160
#define W_ 160
#define PH_ 8
#define PW_ 64
#define HW_ (H_ * W_)
#define NB_ (PH_ * PW_)  // 512 bins per roi

typedef float nfloat4 __attribute__((ext_vector_type(4)));
typedef _Float16 half8 __attribute__((ext_vector_type(8)));   // 16 B

__device__ __forceinline__ void roi_transform(const float* __restrict__ rois,
                                              int n, float* __restrict__ g) {
#pragma clang fp contract(off)
    const float* r = rois + n * 6;
    float bidx = r[0];
    float cx = r[1], cy = r[2], hh = r[3], ww = r[4], ang = r[5];
    float theta = ang * 0.017453292519943295f;
    double td = (double)theta;
    float a = (float)cos(td);
    float s = (float)sin(td);
    float Sx = (ww * 0.25f) / 64.0f;
    float Sy = (hh * 0.25f) / 8.0f;
    float Dx = cx * 0.25f;
    float Dy = cy * 0.25f;
    float M00 = a * Sx;
    float M01 = s * Sy;
    float M02 = ((M00 * -32.0f) + (M01 * -4.0f)) + Dx;
    float M10 = (-s) * Sx;
    float M11 = a * Sy;
    float M12 = ((M10 * -32.0f) + (M11 * -4.0f)) + Dy;
    float* o = g + n * 8;
    o[0] = bidx;
    o[1] = M00; o[2] = M01; o[3] = M02;
    o[4] = M10; o[5] = M11; o[6] = M12;
    o[7] = 0.0f;
}

// NCHW f32 (B,32,25600) -> NHWC fp16 (B,25600,32).
// Blocks (x<ceil(N/256), y==0) also compute roi transforms into g.
__global__ __launch_bounds__(256) void transpose_nhwc(
    const float* __restrict__ feat, _Float16* __restrict__ ft,
    const float* __restrict__ rois, float* __restrict__ g, int N) {
    __shared__ float tile[C_][65];
    int t = threadIdx.x;

    if (blockIdx.y == 0) {
        int n = blockIdx.x * 256 + t;
        if (n < N) roi_transform(rois, n, g);
    }

    int b   = blockIdx.y;
    int hw0 = blockIdx.x * 64;

    // read: 512 float4-units along hw. unit v: c=v>>4, w4=(v&15)*4
#pragma unroll
    for (int i = 0; i < 2; ++i) {
        int v  = i * 256 + t;
        int c  = v >> 4;
        int w4 = (v & 15) * 4;
        const nfloat4 f = __builtin_nontemporal_load(
            (const nfloat4*)&feat[((b * C_ + c) * HW_) + hw0 + w4]);
        tile[c][w4 + 0] = f.x;
        tile[c][w4 + 1] = f.y;
        tile[c][w4 + 2] = f.z;
        tile[c][w4 + 3] = f.w;
    }
    __syncthreads();

    // write: thread t -> pixel p=t>>2, channels c8=(t&3)*8; one 16B store.
    {
        int p  = t >> 2;
        int c8 = (t & 3) * 8;
        half8 o;
#pragma unroll
        for (int k = 0; k < 8; ++k) o[k] = (_Float16)tile[c8 + k][p];
        *(half8*)&ft[((size_t)b * HW_ + hw0 + p) * C_ + c8] = o;
    }
}

// Block = 64 consecutive bins of one roi. 256 threads, NO LDS, NO barrier.
// Thread t: bin bl_=t>>2, channels c8=(t&3)*8. Geometry in registers.
__global__ __launch_bounds__(256) void rroi_nhwc(
    const _Float16* __restrict__ ft, const float* __restrict__ g,
    float* __restrict__ out) {
    int blk = blockIdx.x;
    int n   = blk >> 3;   // wave-uniform -> g loads scalarize
    int seg = blk & 7;
    int t   = threadIdx.x;

    int bl_ = t >> 2;          // bin within segment, 0..63
    int c8  = (t & 3) * 8;     // first of 8 channels

    int pos, dx, dyw;
    float4 w4;
    {
#pragma clang fp contract(off)
        int bin = seg * 64 + bl_;  // = ph*64+pw
        int pw = bin & 63;
        int ph = bin >> 6;
        const float* gg = g + n * 8;
        int   b   = (int)gg[0];
        float M00 = gg[1], M01 = gg[2], M02 = gg[3];
        float M10 = gg[4], M11 = gg[5], M12 = gg[6];

        float pwf  = (float)pw, phf = (float)ph;
        float pwf1 = pwf + 1.0f, phf1 = phf + 1.0f;
        // corners, reference op order: (M00*px + M01*py) + M02
        float X0 = (M00 * pwf  + M01 * phf ) + M02;
        float X1 = (M00 * pwf  + M01 * phf1) + M02;
        float X2 = (M00 * pwf1 + M01 * phf ) + M02;
        float X3 = (M00 * pwf1 + M01 * phf1) + M02;
        float Y0 = (M10 * pwf  + M11 * phf ) + M12;
        float Y1 = (M10 * pwf  + M11 * phf1) + M12;
        float Y2 = (M10 * pwf1 + M11 * phf ) + M12;
        float Y3 = (M10 * pwf1 + M11 * phf1) + M12;

        float minX = fminf(fminf(X0, X1), fminf(X2, X3));
        float maxX = fmaxf(fmaxf(X0, X1), fmaxf(X2, X3));
        float minY = fminf(fminf(Y0, Y1), fminf(Y2, Y3));
        float maxY = fmaxf(fmaxf(Y0, Y1), fmaxf(Y2, Y3));

        float left   = fmaxf(floorf(minX + 0.5f), 0.0f);
        float right  = fminf(floorf(maxX + 0.5f), (float)(W_ - 1));
        float top    = fmaxf(floorf(minY + 0.5f), 0.0f);
        float bottom = fminf(floorf(maxY + 0.5f), (float)(H_ - 1));

        float bcx = (left + right) * 0.5f;
        float bcy = (top + bottom) * 0.5f;
        float bl = floorf(bcx), br = ceilf(bcx);
        float bt = floorf(bcy), bb = ceilf(bcy);
        float rx = bcx - bl;  // exactly 0 or 0.5
        float ry = bcy - bt;

        bool v_l = (bl > -1.0f) && (bl < (float)W_);
        bool v_r = (br > -1.0f) && (br < (float)W_);
        bool v_t = (bt > -1.0f) && (bt < (float)H_);
        bool v_b = (bb > -1.0f) && (bb < (float)H_);

        float omrx = 1.0f - rx, omry = 1.0f - ry;
        w4.x = (v_t && v_l) ? (omrx * omry) : 0.0f;
        w4.y = (v_t && v_r) ? (rx   * omry) : 0.0f;
        w4.z = (v_b && v_l) ? (omrx * ry  ) : 0.0f;
        w4.w = (v_b && v_r) ? (rx   * ry  ) : 0.0f;

        int xl = (int)fminf(fmaxf(bl, 0.0f), (float)(W_ - 1));
        int xr = (int)fminf(fmaxf(br, 0.0f), (float)(W_ - 1));
        int yt = (int)fminf(fmaxf(bt, 0.0f), (float)(H_ - 1));
        int yb = (int)fminf(fmaxf(bb, 0.0f), (float)(H_ - 1));

        pos = b * HW_ + yt * W_ + xl;  // NHWC pixel index
        dx  = xr - xl;
        dyw = (yb - yt) * W_;
    }

    // Predicated gather: weights are EXACTLY 0 for skippable corners
    // (rx/ry in {0,0.5}; validity folded in). Zero registers -> blend
    // contributes exact 0.0f, identical to reference. ~2.25/4 loads avg.
    const half8* f0 = (const half8*)(ft + (size_t)pos * C_ + c8);
    half8 a0 = (half8)(_Float16)0.0f;
    half8 a1 = a0, a2 = a0, a3 = a0;
    if (w4.x != 0.0f) a0 = f0[0];
    if (w4.y != 0.0f) a1 = f0[dx * 4];
    if (w4.z != 0.0f) a2 = f0[dyw * 4];
    if (w4.w != 0.0f) a3 = f0[(dx + dyw) * 4];

    // Blend + direct NT store. For fixed channel c8+k, the wave's 16 lanes
    // (bl_=t>>2 = 0..15 consecutive) write one full 64B line per inst.
    float* ob = out + ((size_t)n * C_ + c8) * NB_ + seg * 64 + bl_;
    {
#pragma clang fp contract(off)
#pragma unroll
        for (int k = 0; k < 8; ++k) {
            float o = ((w4.x * (float)a0[k] + w4.y * (float)a1[k]) +
                       w4.z * (float)a2[k]) +
                      w4.w * (float)a3[k];
            __builtin_nontemporal_store(o, ob + k * NB_);
        }
    }
}

// Fallback (R1, known-good): thread per output, full geometry recompute.
__global__ __launch_bounds__(256) void roi_prep(const float* __restrict__ rois,
                                                float* __restrict__ g, int N) {
    int n = blockIdx.x * 256 + threadIdx.x;
    if (n < N) roi_transform(rois, n, g);
}

__global__ __launch_bounds__(256) void rroi_fallback(
    const float* __restrict__ feat, const float* __restrict__ g,
    float* __restrict__ out, int total) {
#pragma clang fp contract(off)
    int idx = blockIdx.x * 256 + threadIdx.x;
    if (idx >= total) return;
    int pw = idx & 63;
    int ph = (idx >> 6) & 7;
    int c  = (idx >> 9) & 31;
    int n  = idx >> 14;
    const float* gg = g + n * 8;
    int   b   = (int)gg[0];
    float M00 = gg[1], M01 = gg[2], M02 = gg[3];
    float M10 = gg[4], M11 = gg[5], M12 = gg[6];
    float pwf  = (float)pw, phf = (float)ph;
    float pwf1 = pwf + 1.0f, phf1 = phf + 1.0f;
    float X0 = (M00 * pwf  + M01 * phf ) + M02;
    float X1 = (M00 * pwf  + M01 * phf1) + M02;
    float X2 = (M00 * pwf1 + M01 * phf ) + M02;
    float X3 = (M00 * pwf1 + M01 * phf1) + M02;
    float Y0 = (M10 * pwf  + M11 * phf ) + M12;
    float Y1 = (M10 * pwf  + M11 * phf1) + M12;
    float Y2 = (M10 * pwf1 + M11 * phf ) + M12;
    float Y3 = (M10 * pwf1 + M11 * phf1) + M12;
    float minX = fminf(fminf(X0, X1), fminf(X2, X3));
    float maxX = fmaxf(fmaxf(X0, X1), fmaxf(X2, X3));
    float minY = fminf(fminf(Y0, Y1), fminf(Y2, Y3));
    float maxY = fmaxf(fmaxf(Y0, Y1), fmaxf(Y2, Y3));
    float left   = fmaxf(floorf(minX + 0.5f), 0.0f);
    float right  = fminf(floorf(maxX + 0.5f), (float)(W_ - 1));
    float top    = fmaxf(floorf(minY + 0.5f), 0.0f);
    float bottom = fminf(floorf(maxY + 0.5f), (float)(H_ - 1));
    float bcx = (left + right) * 0.5f;
    float bcy = (top + bottom) * 0.5f;
    float bl = floorf(bcx), br = ceilf(bcx);
    float bt = floorf(bcy), bb = ceilf(bcy);
    float rx = bcx - bl;
    float ry = bcy - bt;
    const float* fc = feat + (size_t)(b * C_ + c) * HW_;
    auto gat = [&](float yi, float xi) -> float {
        bool valid = (yi > -1.0f) && (xi > -1.0f) && (yi < (float)H_) &&
                     (xi < (float)W_);
        int yc = (int)fminf(fmaxf(yi, 0.0f), (float)(H_ - 1));
        int xc = (int)fminf(fmaxf(xi, 0.0f), (float)(W_ - 1));
        float v = fc[yc * W_ + xc];
        return valid ? v : 0.0f;
    };
    float vlt = gat(bt, bl);
    float vrt = gat(bt, br);
    float vlb = gat(bb, bl);
    float vrb = gat(bb, br);
    float omrx = 1.0f - rx, omry = 1.0f - ry;
    float o = (((omrx * omry) * vlt + (rx * omry) * vrt) + (omrx * ry) * vlb) +
              (rx * ry) * vrb;
    out[idx] = o;
}

extern "C" void kernel_launch(void* const* d_in, const int* in_sizes, int n_in,
                              void* d_out, int out_size, void* d_ws,
                              size_t ws_size, hipStream_t stream) {
    const float* feat = (const float*)d_in[0];
    const float* rois = (const float*)d_in[1];
    float* out = (float*)d_out;
    int N = in_sizes[1] / 6;
    int B = in_sizes[0] / (C_ * HW_);

    size_t gBytes  = ((size_t)N * 8 * sizeof(float) + 255) & ~(size_t)255;
    size_t ftBytes = (size_t)B * HW_ * C_ * sizeof(_Float16);
    size_t needed  = gBytes + ftBytes;

    if (ws_size >= needed) {
        float*    g  = (float*)d_ws;
        _Float16* ft = (_Float16*)((char*)d_ws + gBytes);
        hipLaunchKernelGGL(transpose_nhwc, dim3(HW_ / 64, B), dim3(256), 0,
                           stream, feat, ft, rois, g, N);
        hipLaunchKernelGGL(rroi_nhwc, dim3(N * 8), dim3(256), 0, stream, ft, g,
                           out);
    } else {
        float* g = (float*)d_ws;  // N*8 floats
        hipLaunchKernelGGL(roi_prep, dim3((N + 255) / 256), dim3(256), 0,
                           stream, rois, g, N);
        hipLaunchKernelGGL(rroi_fallback, dim3((out_size + 255) / 256),
                           dim3(256), 0, stream, feat, g, out, out_size);
    }
}

// Round 4
// 100.475 us; speedup vs baseline: 1.0319x; 1.0319x over previous
//
#include <hip/hip_runtime.h>
#include <math.h>

// RRoIAlign: features (8,32,160,160) f32, rois (1024,6) f32
// out (1024,32,8,64) f32.  POOLED_H=8, POOLED_W=64, SPATIAL_SCALE=0.25
//
// R11 = revert to R9 (best measured: 100.5us). R10's predicated gather +
// direct NT scalar stores regressed (+3.2us): exec-mask overhead > skipped
// loads (zero-weight corners were duplicate-address L1 broadcasts anyway),
// and 8x scalar dword NT stores issue worse than LDS-staged 2x dwordx4.
//
// Sensitivity record (kept for future sessions): R8 XCD-affinity +1.2us
// (gather NOT L2-miss-bound), R9 single-barrier/reg-geometry -2.3us,
// R10 predication+LDS-less stores +3.2us. Timed stream carries ~55us of
// harness poison fills (256MiB ws @44us + out @11us); kernels are near
// their floors: transpose ~39MB stream, rroi ~67MB NT-store-bound.
//
// R9: single-barrier rroi; per-thread register geometry (4x redundant VALU
// is free); gather half8 16B/lane; one barrier before s_out transpose.
// R7: fp16 NHWC intermediate (halves the transpose-trick's HBM overhead).
// Feature fp16 rounding error <= |v|*2^-11 ~ 0.003 << 0.101 threshold.
//
// NUMERICS (frozen since R1): geometry fp contract(off) + reference op order;
// trig double->f32; blend ((w0*a+w1*b)+w2*c)+w3*d contract off. Do not
// re-order. absmax was 0.0 with f32 intermediate; fp16 adds ~3e-3.

#define C_ 32
#define H_ 160
#define W_ 160
#define PH_ 8
#define PW_ 64
#define HW_ (H_ * W_)
#define NB_ (PH_ * PW_)  // 512 bins per roi

typedef float nfloat4 __attribute__((ext_vector_type(4)));
typedef _Float16 half8 __attribute__((ext_vector_type(8)));   // 16 B

__device__ __forceinline__ void roi_transform(const float* __restrict__ rois,
                                              int n, float* __restrict__ g) {
#pragma clang fp contract(off)
    const float* r = rois + n * 6;
    float bidx = r[0];
    float cx = r[1], cy = r[2], hh = r[3], ww = r[4], ang = r[5];
    float theta = ang * 0.017453292519943295f;
    double td = (double)theta;
    float a = (float)cos(td);
    float s = (float)sin(td);
    float Sx = (ww * 0.25f) / 64.0f;
    float Sy = (hh * 0.25f) / 8.0f;
    float Dx = cx * 0.25f;
    float Dy = cy * 0.25f;
    float M00 = a * Sx;
    float M01 = s * Sy;
    float M02 = ((M00 * -32.0f) + (M01 * -4.0f)) + Dx;
    float M10 = (-s) * Sx;
    float M11 = a * Sy;
    float M12 = ((M10 * -32.0f) + (M11 * -4.0f)) + Dy;
    float* o = g + n * 8;
    o[0] = bidx;
    o[1] = M00; o[2] = M01; o[3] = M02;
    o[4] = M10; o[5] = M11; o[6] = M12;
    o[7] = 0.0f;
}

// NCHW f32 (B,32,25600) -> NHWC fp16 (B,25600,32).
// Blocks (x<ceil(N/256), y==0) also compute roi transforms into g.
__global__ __launch_bounds__(256) void transpose_nhwc(
    const float* __restrict__ feat, _Float16* __restrict__ ft,
    const float* __restrict__ rois, float* __restrict__ g, int N) {
    __shared__ float tile[C_][65];
    int t = threadIdx.x;

    if (blockIdx.y == 0) {
        int n = blockIdx.x * 256 + t;
        if (n < N) roi_transform(rois, n, g);
    }

    int b   = blockIdx.y;
    int hw0 = blockIdx.x * 64;

    // read: 512 float4-units along hw. unit v: c=v>>4, w4=(v&15)*4
#pragma unroll
    for (int i = 0; i < 2; ++i) {
        int v  = i * 256 + t;
        int c  = v >> 4;
        int w4 = (v & 15) * 4;
        const nfloat4 f = __builtin_nontemporal_load(
            (const nfloat4*)&feat[((b * C_ + c) * HW_) + hw0 + w4]);
        tile[c][w4 + 0] = f.x;
        tile[c][w4 + 1] = f.y;
        tile[c][w4 + 2] = f.z;
        tile[c][w4 + 3] = f.w;
    }
    __syncthreads();

    // write: thread t -> pixel p=t>>2, channels c8=(t&3)*8; one 16B store.
    {
        int p  = t >> 2;
        int c8 = (t & 3) * 8;
        half8 o;
#pragma unroll
        for (int k = 0; k < 8; ++k) o[k] = (_Float16)tile[c8 + k][p];
        *(half8*)&ft[((size_t)b * HW_ + hw0 + p) * C_ + c8] = o;
    }
}

// Block = 64 consecutive bins of one roi. 256 threads, ONE barrier.
// Thread t: bin bl_=t>>2, channels c8=(t&3)*8. Geometry in registers.
__global__ __launch_bounds__(256) void rroi_nhwc(
    const _Float16* __restrict__ ft, const float* __restrict__ g,
    float* __restrict__ out) {
    __shared__ float s_out[C_ * 65];  // [c][bin], pad 65 (2-way, free)

    int blk = blockIdx.x;
    int n   = blk >> 3;   // wave-uniform -> g loads scalarize
    int seg = blk & 7;
    int t   = threadIdx.x;

    int bl_ = t >> 2;          // bin within segment, 0..63
    int c8  = (t & 3) * 8;     // first of 8 channels

    int pos, dx, dyw;
    float4 w4;
    {
#pragma clang fp contract(off)
        int bin = seg * 64 + bl_;  // = ph*64+pw
        int pw = bin & 63;
        int ph = bin >> 6;
        const float* gg = g + n * 8;
        int   b   = (int)gg[0];
        float M00 = gg[1], M01 = gg[2], M02 = gg[3];
        float M10 = gg[4], M11 = gg[5], M12 = gg[6];

        float pwf  = (float)pw, phf = (float)ph;
        float pwf1 = pwf + 1.0f, phf1 = phf + 1.0f;
        // corners, reference op order: (M00*px + M01*py) + M02
        float X0 = (M00 * pwf  + M01 * phf ) + M02;
        float X1 = (M00 * pwf  + M01 * phf1) + M02;
        float X2 = (M00 * pwf1 + M01 * phf ) + M02;
        float X3 = (M00 * pwf1 + M01 * phf1) + M02;
        float Y0 = (M10 * pwf  + M11 * phf ) + M12;
        float Y1 = (M10 * pwf  + M11 * phf1) + M12;
        float Y2 = (M10 * pwf1 + M11 * phf ) + M12;
        float Y3 = (M10 * pwf1 + M11 * phf1) + M12;

        float minX = fminf(fminf(X0, X1), fminf(X2, X3));
        float maxX = fmaxf(fmaxf(X0, X1), fmaxf(X2, X3));
        float minY = fminf(fminf(Y0, Y1), fminf(Y2, Y3));
        float maxY = fmaxf(fmaxf(Y0, Y1), fmaxf(Y2, Y3));

        float left   = fmaxf(floorf(minX + 0.5f), 0.0f);
        float right  = fminf(floorf(maxX + 0.5f), (float)(W_ - 1));
        float top    = fmaxf(floorf(minY + 0.5f), 0.0f);
        float bottom = fminf(floorf(maxY + 0.5f), (float)(H_ - 1));

        float bcx = (left + right) * 0.5f;
        float bcy = (top + bottom) * 0.5f;
        float bl = floorf(bcx), br = ceilf(bcx);
        float bt = floorf(bcy), bb = ceilf(bcy);
        float rx = bcx - bl;  // exactly 0 or 0.5
        float ry = bcy - bt;

        bool v_l = (bl > -1.0f) && (bl < (float)W_);
        bool v_r = (br > -1.0f) && (br < (float)W_);
        bool v_t = (bt > -1.0f) && (bt < (float)H_);
        bool v_b = (bb > -1.0f) && (bb < (float)H_);

        float omrx = 1.0f - rx, omry = 1.0f - ry;
        w4.x = (v_t && v_l) ? (omrx * omry) : 0.0f;
        w4.y = (v_t && v_r) ? (rx   * omry) : 0.0f;
        w4.z = (v_b && v_l) ? (omrx * ry  ) : 0.0f;
        w4.w = (v_b && v_r) ? (rx   * ry  ) : 0.0f;

        int xl = (int)fminf(fmaxf(bl, 0.0f), (float)(W_ - 1));
        int xr = (int)fminf(fmaxf(br, 0.0f), (float)(W_ - 1));
        int yt = (int)fminf(fmaxf(bt, 0.0f), (float)(H_ - 1));
        int yb = (int)fminf(fmaxf(bb, 0.0f), (float)(H_ - 1));

        pos = b * HW_ + yt * W_ + xl;  // NHWC pixel index
        dx  = xr - xl;
        dyw = (yb - yt) * W_;
    }

    // Gather+blend: 16B/lane per corner. Per bin: 4 lanes x 16B = one 64B
    // line per corner -> coalesced dwordx4.
    {
#pragma clang fp contract(off)
        const half8* f0 = (const half8*)(ft + (size_t)pos * C_ + c8);
        half8 a0 = f0[0];
        half8 a1 = f0[dx * 4];
        half8 a2 = f0[dyw * 4];
        half8 a3 = f0[(dx + dyw) * 4];

#pragma unroll
        for (int k = 0; k < 8; ++k) {
            float o = ((w4.x * (float)a0[k] + w4.y * (float)a1[k]) +
                       w4.z * (float)a2[k]) +
                      w4.w * (float)a3[k];
            s_out[(c8 + k) * 65 + bl_] = o;
        }
    }
    __syncthreads();

    // Store: 512 float4-units along bins. unit v: c=v>>4, b4=(v&15)*4.
    int obase = n * (C_ * NB_) + seg * 64;
#pragma unroll
    for (int i = 0; i < 2; ++i) {
        int v  = i * 256 + t;
        int cc = v >> 4;
        int b4 = (v & 15) * 4;
        nfloat4 o;
        o.x = s_out[cc * 65 + b4 + 0];
        o.y = s_out[cc * 65 + b4 + 1];
        o.z = s_out[cc * 65 + b4 + 2];
        o.w = s_out[cc * 65 + b4 + 3];
        __builtin_nontemporal_store(o, (nfloat4*)&out[obase + cc * NB_ + b4]);
    }
}

// Fallback (R1, known-good): thread per output, full geometry recompute.
__global__ __launch_bounds__(256) void roi_prep(const float* __restrict__ rois,
                                                float* __restrict__ g, int N) {
    int n = blockIdx.x * 256 + threadIdx.x;
    if (n < N) roi_transform(rois, n, g);
}

__global__ __launch_bounds__(256) void rroi_fallback(
    const float* __restrict__ feat, const float* __restrict__ g,
    float* __restrict__ out, int total) {
#pragma clang fp contract(off)
    int idx = blockIdx.x * 256 + threadIdx.x;
    if (idx >= total) return;
    int pw = idx & 63;
    int ph = (idx >> 6) & 7;
    int c  = (idx >> 9) & 31;
    int n  = idx >> 14;
    const float* gg = g + n * 8;
    int   b   = (int)gg[0];
    float M00 = gg[1], M01 = gg[2], M02 = gg[3];
    float M10 = gg[4], M11 = gg[5], M12 = gg[6];
    float pwf  = (float)pw, phf = (float)ph;
    float pwf1 = pwf + 1.0f, phf1 = phf + 1.0f;
    float X0 = (M00 * pwf  + M01 * phf ) + M02;
    float X1 = (M00 * pwf  + M01 * phf1) + M02;
    float X2 = (M00 * pwf1 + M01 * phf ) + M02;
    float X3 = (M00 * pwf1 + M01 * phf1) + M02;
    float Y0 = (M10 * pwf  + M11 * phf ) + M12;
    float Y1 = (M10 * pwf  + M11 * phf1) + M12;
    float Y2 = (M10 * pwf1 + M11 * phf ) + M12;
    float Y3 = (M10 * pwf1 + M11 * phf1) + M12;
    float minX = fminf(fminf(X0, X1), fminf(X2, X3));
    float maxX = fmaxf(fmaxf(X0, X1), fmaxf(X2, X3));
    float minY = fminf(fminf(Y0, Y1), fminf(Y2, Y3));
    float maxY = fmaxf(fmaxf(Y0, Y1), fmaxf(Y2, Y3));
    float left   = fmaxf(floorf(minX + 0.5f), 0.0f);
    float right  = fminf(floorf(maxX + 0.5f), (float)(W_ - 1));
    float top    = fmaxf(floorf(minY + 0.5f), 0.0f);
    float bottom = fminf(floorf(maxY + 0.5f), (float)(H_ - 1));
    float bcx = (left + right) * 0.5f;
    float bcy = (top + bottom) * 0.5f;
    float bl = floorf(bcx), br = ceilf(bcx);
    float bt = floorf(bcy), bb = ceilf(bcy);
    float rx = bcx - bl;
    float ry = bcy - bt;
    const float* fc = feat + (size_t)(b * C_ + c) * HW_;
    auto gat = [&](float yi, float xi) -> float {
        bool valid = (yi > -1.0f) && (xi > -1.0f) && (yi < (float)H_) &&
                     (xi < (float)W_);
        int yc = (int)fminf(fmaxf(yi, 0.0f), (float)(H_ - 1));
        int xc = (int)fminf(fmaxf(xi, 0.0f), (float)(W_ - 1));
        float v = fc[yc * W_ + xc];
        return valid ? v : 0.0f;
    };
    float vlt = gat(bt, bl);
    float vrt = gat(bt, br);
    float vlb = gat(bb, bl);
    float vrb = gat(bb, br);
    float omrx = 1.0f - rx, omry = 1.0f - ry;
    float o = (((omrx * omry) * vlt + (rx * omry) * vrt) + (omrx * ry) * vlb) +
              (rx * ry) * vrb;
    out[idx] = o;
}

extern "C" void kernel_launch(void* const* d_in, const int* in_sizes, int n_in,
                              void* d_out, int out_size, void* d_ws,
                              size_t ws_size, hipStream_t stream) {
    const float* feat = (const float*)d_in[0];
    const float* rois = (const float*)d_in[1];
    float* out = (float*)d_out;
    int N = in_sizes[1] / 6;
    int B = in_sizes[0] / (C_ * HW_);

    size_t gBytes  = ((size_t)N * 8 * sizeof(float) + 255) & ~(size_t)255;
    size_t ftBytes = (size_t)B * HW_ * C_ * sizeof(_Float16);
    size_t needed  = gBytes + ftBytes;

    if (ws_size >= needed) {
        float*    g  = (float*)d_ws;
        _Float16* ft = (_Float16*)((char*)d_ws + gBytes);
        hipLaunchKernelGGL(transpose_nhwc, dim3(HW_ / 64, B), dim3(256), 0,
                           stream, feat, ft, rois, g, N);
        hipLaunchKernelGGL(rroi_nhwc, dim3(N * 8), dim3(256), 0, stream, ft, g,
                           out);
    } else {
        float* g = (float*)d_ws;  // N*8 floats
        hipLaunchKernelGGL(roi_prep, dim3((N + 255) / 256), dim3(256), 0,
                           stream, rois, g, N);
        hipLaunchKernelGGL(rroi_fallback, dim3((out_size + 255) / 256),
                           dim3(256), 0, stream, feat, g, out, out_size);
    }
}